// Round 3
// baseline (22.495 us; speedup 1.0000x reference)
//
#include <hip/hip_runtime.h>

#define ALPHA  0.7f
#define MARGIN 0.5f
#define TI 64    // i-tile (staged in LDS as float2)
#define TJ 256   // j-tile per block = 64 threads * JR
#define JR 4     // j's per thread, loaded as float4

// Triangular tiling with 1-wave blocks.
// j-tile jt (width 256), i-tiles it = 0 .. 4*jt+3 (height 64):
//   it <  4*jt  -> full tile  (all i < all j, no predicate)
//   it >= 4*jt  -> partial    (per-pair global i < j predicate)
// Column jt starts at K(jt) = 2*jt*(jt+1).  NB = 2*NJ*(NJ+1). B=8192 -> 2112.
__global__ __launch_bounds__(64) void pair_kernel(const float* __restrict__ p,
                                                  const float* __restrict__ t,
                                                  int B,
                                                  float* __restrict__ bsum,
                                                  float* __restrict__ bmse,
                                                  int*   __restrict__ bcnt) {
    const int bid = blockIdx.x;
    int jt = (int)((sqrtf(1.0f + 2.0f * (float)bid) - 1.0f) * 0.5f);
    while (2 * (jt + 1) * (jt + 2) <= bid) ++jt;
    while (2 * jt * (jt + 1) > bid) --jt;
    const int it  = bid - 2 * jt * (jt + 1);

    const int tid   = threadIdx.x;          // 0..63, one wave
    const int ig0   = it * TI;
    const int jbase = jt * TJ;
    const int j0    = jbase + tid * JR;     // first of this thread's 4 j's

    __shared__ float2 s_tp[TI];
    {
        const int ig = ig0 + tid;
        float2 v;
        if (ig < B) { v.x = t[ig]; v.y = p[ig]; }
        else        { v.x = 0.0f;  v.y = 0.0f;  }
        s_tp[tid] = v;
    }
    __syncthreads();

    // per-thread j data (registers)
    float tjv[JR], pjv[JR];
    bool  jvb[JR];
    if (j0 + JR <= B) {
        const float4 tv = *reinterpret_cast<const float4*>(t + j0);
        const float4 pv = *reinterpret_cast<const float4*>(p + j0);
        tjv[0] = tv.x; tjv[1] = tv.y; tjv[2] = tv.z; tjv[3] = tv.w;
        pjv[0] = pv.x; pjv[1] = pv.y; pjv[2] = pv.z; pjv[3] = pv.w;
        jvb[0] = jvb[1] = jvb[2] = jvb[3] = true;
    } else {
        #pragma unroll
        for (int k = 0; k < JR; ++k) {
            const int jg = j0 + k;
            jvb[k] = jg < B;
            tjv[k] = jvb[k] ? t[jg] : 0.0f;
            pjv[k] = jvb[k] ? p[jg] : 0.0f;
        }
    }
    unsigned long long jm[JR];
    #pragma unroll
    for (int k = 0; k < JR; ++k) jm[k] = __ballot(jvb[k]);

    float sum[JR] = {0.0f, 0.0f, 0.0f, 0.0f};
    int   cnt = 0;            // wave-uniform (SGPR) via ballot/popc
    float msev = 0.0f;

    if (it == 4 * jt) {       // exactly one block per j-column folds the MSE
        #pragma unroll
        for (int k = 0; k < JR; ++k) {
            const float d = pjv[k] - tjv[k];
            msev += jvb[k] ? d * d : 0.0f;
        }
    }

    if (it < 4 * jt) {
        // -------- full tile: no i<j predicate --------
        #pragma unroll 8
        for (int ii = 0; ii < TI; ++ii) {
            const float2 itp = s_tp[ii];
            #pragma unroll
            for (int k = 0; k < JR; ++k) {
                const float dt = itp.x - tjv[k];
                const float dp = itp.y - pjv[k];
                const unsigned sg = __float_as_uint(dt) & 0x80000000u;
                const float sdp = __uint_as_float(__float_as_uint(dp) ^ sg);
                const float v = fmaxf(MARGIN - sdp, 0.0f);
                const bool val = (dt != 0.0f);
                sum[k] += val ? v : 0.0f;
                cnt += (int)__popcll(__ballot(val) & jm[k]);
            }
        }
    } else {
        // -------- partial tile: need global i < j --------
        int jloc[JR];
        #pragma unroll
        for (int k = 0; k < JR; ++k) jloc[k] = j0 + k - ig0; // valid iff ii < jloc[k]
        #pragma unroll 4
        for (int ii = 0; ii < TI; ++ii) {
            const float2 itp = s_tp[ii];
            #pragma unroll
            for (int k = 0; k < JR; ++k) {
                const float dt = itp.x - tjv[k];
                const float dp = itp.y - pjv[k];
                const unsigned sg = __float_as_uint(dt) & 0x80000000u;
                const float sdp = __uint_as_float(__float_as_uint(dp) ^ sg);
                const float v = fmaxf(MARGIN - sdp, 0.0f);
                const bool val = (dt != 0.0f) && (ii < jloc[k]);
                sum[k] += val ? v : 0.0f;
                cnt += (int)__popcll(__ballot(val) & jm[k]);
            }
        }
    }

    // zero garbage sums from invalid-j lanes, collapse JR, butterfly over wave
    float stot = 0.0f;
    #pragma unroll
    for (int k = 0; k < JR; ++k) stot += jvb[k] ? sum[k] : 0.0f;
    for (int off = 32; off > 0; off >>= 1) {
        stot += __shfl_down(stot, off);
        msev += __shfl_down(msev, off);
    }
    if (tid == 0) {
        bsum[bid] = stot;
        bmse[bid] = msev;
        bcnt[bid] = cnt;     // uniform
    }
}

// Fixed-order deterministic tree reduction over NB partials.
__global__ __launch_bounds__(256) void finalize_kernel(const float* __restrict__ bsum,
                                                       const float* __restrict__ bmse,
                                                       const int*   __restrict__ bcnt,
                                                       int NB, int B,
                                                       float* __restrict__ out) {
    const int tid = threadIdx.x;
    double S = 0.0, M = 0.0;
    long long C = 0;
    for (int k = tid; k < NB; k += 256) {
        S += (double)bsum[k];
        M += (double)bmse[k];
        C += (long long)bcnt[k];
    }
    for (int off = 32; off > 0; off >>= 1) {
        S += __shfl_down(S, off);
        M += __shfl_down(M, off);
        C += __shfl_down(C, off);
    }
    __shared__ double rs[4], rm[4];
    __shared__ long long rc[4];
    const int wid = tid >> 6, lane = tid & 63;
    if (lane == 0) { rs[wid] = S; rm[wid] = M; rc[wid] = C; }
    __syncthreads();
    if (tid == 0) {
        S = rs[0] + rs[1] + rs[2] + rs[3];
        M = rm[0] + rm[1] + rm[2] + rm[3];
        C = rc[0] + rc[1] + rc[2] + rc[3];
        const double mse  = M / (double)B;
        const double rank = (C > 0) ? (S / (double)(C > 1 ? C : 1)) : 0.0;
        out[0] = (float)((double)ALPHA * mse + (double)(1.0f - ALPHA) * rank);
    }
}

extern "C" void kernel_launch(void* const* d_in, const int* in_sizes, int n_in,
                              void* d_out, int out_size, void* d_ws, size_t ws_size,
                              hipStream_t stream) {
    const float* p = (const float*)d_in[0];
    const float* t = (const float*)d_in[1];
    const int B = in_sizes[0];

    const int NJ = (B + TJ - 1) / TJ;
    const int NB = 2 * NJ * (NJ + 1);

    float* bsum = (float*)d_ws;
    float* bmse = bsum + NB;
    int*   bcnt = (int*)(bmse + NB);

    pair_kernel<<<NB, 64, 0, stream>>>(p, t, B, bsum, bmse, bcnt);
    finalize_kernel<<<1, 256, 0, stream>>>(bsum, bmse, bcnt, NB, B, (float*)d_out);
}

// Round 4
// 22.083 us; speedup vs baseline: 1.0187x; 1.0187x over previous
//
#include <hip/hip_runtime.h>

#define ALPHA  0.7f
#define MARGIN 0.5f
#define TI  32    // i-tile height (read via wave-uniform scalar loads)
#define TJN 256   // j-tile width per block = 64 threads * JR
#define JR  4     // j's per thread (float4)

// Triangular tiling, 1-wave (64-thread) blocks, no LDS.
// j-tile jt (width 256): i-tiles it = 0 .. 8*jt+7 (height 32).
//   it <  8*jt -> full tile (all i < all j, no predicate)
//   it >= 8*jt -> partial   (per-pair i<j predicate)
// Column jt starts at K(jt) = 4*jt*(jt+1). NB = 4*NJ*(NJ+1). B=8192 -> 4224.
__global__ __launch_bounds__(64) void pair_kernel(const float* __restrict__ p,
                                                  const float* __restrict__ t,
                                                  int B,
                                                  float* __restrict__ bsum,
                                                  float* __restrict__ bmse,
                                                  int*   __restrict__ bcnt) {
    const int bid = blockIdx.x;
    int jt = (int)((sqrtf((float)bid + 1.0f) - 1.0f) * 0.5f);
    while (4 * (jt + 1) * (jt + 2) <= bid) ++jt;
    while (4 * jt * (jt + 1) > bid) --jt;
    const int it = bid - 4 * jt * (jt + 1);

    const int tid   = threadIdx.x;        // 0..63
    const int ibase = it * TI;
    const int j0    = jt * TJN + tid * JR;

    // per-thread j data in registers
    float tjv[JR], pjv[JR];
    bool  jvb[JR];
    if (j0 + JR <= B) {
        const float4 tv = *reinterpret_cast<const float4*>(t + j0);
        const float4 pv = *reinterpret_cast<const float4*>(p + j0);
        tjv[0] = tv.x; tjv[1] = tv.y; tjv[2] = tv.z; tjv[3] = tv.w;
        pjv[0] = pv.x; pjv[1] = pv.y; pjv[2] = pv.z; pjv[3] = pv.w;
        jvb[0] = jvb[1] = jvb[2] = jvb[3] = true;
    } else {
        #pragma unroll
        for (int k = 0; k < JR; ++k) {
            const int jg = j0 + k;
            jvb[k] = jg < B;
            tjv[k] = jvb[k] ? t[jg] : 0.0f;
            pjv[k] = jvb[k] ? p[jg] : 0.0f;
        }
    }

    float sum[JR] = {0.0f, 0.0f, 0.0f, 0.0f};
    int   ceq  = 0;      // equal-t pairs seen (rare path only)
    int   cbase = 0;     // pairs processed (closed form)
    float msev = 0.0f;

    if (it == 0) {       // one block per j-column folds the MSE
        #pragma unroll
        for (int k = 0; k < JR; ++k) {
            const float d = pjv[k] - tjv[k];
            msev += jvb[k] ? d * d : 0.0f;
        }
    }

    const int ilim = min(TI, B - ibase);

    if (it < 8 * jt) {
        // ---------- full tile: no i<j predicate, unmasked sum ----------
        #pragma unroll 8
        for (int ii = 0; ii < TI; ++ii) {
            const float ti_s = t[ibase + ii];   // wave-uniform -> s_load
            const float pi_s = p[ibase + ii];
            #pragma unroll
            for (int k = 0; k < JR; ++k) {
                const float dt = ti_s - tjv[k];
                const float dp = pi_s - pjv[k];
                const unsigned sg = __float_as_uint(dt) & 0x80000000u;
                const float sdp = __uint_as_float(__float_as_uint(dp) ^ sg);
                const float v = fmaxf(MARGIN - sdp, 0.0f);
                sum[k] += v;
                const bool eq = (dt == 0.0f);
                if (__any(eq)) {                // rare: exact tie handling
                    const bool hit = eq && jvb[k];
                    sum[k] -= hit ? v : 0.0f;
                    ceq    += hit ? 1 : 0;
                }
            }
        }
        int nvj = 0;
        #pragma unroll
        for (int k = 0; k < JR; ++k) nvj += jvb[k] ? 1 : 0;
        cbase = TI * nvj;
    } else if (ilim > 0) {
        // ---------- partial tile: need global i < j ----------
        int jloc[JR];
        #pragma unroll
        for (int k = 0; k < JR; ++k) jloc[k] = j0 + k - ibase;  // valid iff ii < jloc[k]
        #pragma unroll 4
        for (int ii = 0; ii < ilim; ++ii) {
            const float ti_s = t[ibase + ii];
            const float pi_s = p[ibase + ii];
            #pragma unroll
            for (int k = 0; k < JR; ++k) {
                const float dt = ti_s - tjv[k];
                const float dp = pi_s - pjv[k];
                const unsigned sg = __float_as_uint(dt) & 0x80000000u;
                const float sdp = __uint_as_float(__float_as_uint(dp) ^ sg);
                const float v = fmaxf(MARGIN - sdp, 0.0f);
                const bool inr = ii < jloc[k];
                sum[k] += inr ? v : 0.0f;
                const bool eq = (dt == 0.0f);
                if (__any(eq)) {                // rare: exact tie handling
                    const bool hit = eq && inr && jvb[k];
                    sum[k] -= hit ? v : 0.0f;
                    ceq    += hit ? 1 : 0;
                }
            }
        }
        #pragma unroll
        for (int k = 0; k < JR; ++k) {
            const int c = min(max(jloc[k], 0), ilim);
            cbase += jvb[k] ? c : 0;
        }
    }

    // epilogue: zero invalid-j sums, collapse, wave butterfly
    float stot = 0.0f;
    #pragma unroll
    for (int k = 0; k < JR; ++k) stot += jvb[k] ? sum[k] : 0.0f;
    int cnt = cbase - ceq;

    for (int off = 32; off > 0; off >>= 1) {
        stot += __shfl_down(stot, off);
        msev += __shfl_down(msev, off);
        cnt  += __shfl_down(cnt, off);
    }
    if (tid == 0) {
        bsum[bid] = stot;
        bmse[bid] = msev;
        bcnt[bid] = cnt;
    }
}

// Fixed-order deterministic tree reduction over NB partials.
__global__ __launch_bounds__(256) void finalize_kernel(const float* __restrict__ bsum,
                                                       const float* __restrict__ bmse,
                                                       const int*   __restrict__ bcnt,
                                                       int NB, int B,
                                                       float* __restrict__ out) {
    const int tid = threadIdx.x;
    double S = 0.0, M = 0.0;
    long long C = 0;
    for (int k = tid; k < NB; k += 256) {
        S += (double)bsum[k];
        M += (double)bmse[k];
        C += (long long)bcnt[k];
    }
    for (int off = 32; off > 0; off >>= 1) {
        S += __shfl_down(S, off);
        M += __shfl_down(M, off);
        C += __shfl_down(C, off);
    }
    __shared__ double rs[4], rm[4];
    __shared__ long long rc[4];
    const int wid = tid >> 6, lane = tid & 63;
    if (lane == 0) { rs[wid] = S; rm[wid] = M; rc[wid] = C; }
    __syncthreads();
    if (tid == 0) {
        S = rs[0] + rs[1] + rs[2] + rs[3];
        M = rm[0] + rm[1] + rm[2] + rm[3];
        C = rc[0] + rc[1] + rc[2] + rc[3];
        const double mse  = M / (double)B;
        const double rank = (C > 0) ? (S / (double)(C > 1 ? C : 1)) : 0.0;
        out[0] = (float)((double)ALPHA * mse + (double)(1.0f - ALPHA) * rank);
    }
}

extern "C" void kernel_launch(void* const* d_in, const int* in_sizes, int n_in,
                              void* d_out, int out_size, void* d_ws, size_t ws_size,
                              hipStream_t stream) {
    const float* p = (const float*)d_in[0];
    const float* t = (const float*)d_in[1];
    const int B = in_sizes[0];

    const int NJ = (B + TJN - 1) / TJN;
    const int NB = 4 * NJ * (NJ + 1);

    float* bsum = (float*)d_ws;
    float* bmse = bsum + NB;
    int*   bcnt = (int*)(bmse + NB);

    pair_kernel<<<NB, 64, 0, stream>>>(p, t, B, bsum, bmse, bcnt);
    finalize_kernel<<<1, 256, 0, stream>>>(bsum, bmse, bcnt, NB, B, (float*)d_out);
}